// Round 2
// baseline (820.378 us; speedup 1.0000x reference)
//
#include <hip/hip_runtime.h>

// Problem constants
#define NBANDS 64
#define LATENT 256
#define HIDDEN 512
#define GQ 8
#define KQ 1024
#define GD 32
#define NROWS 16000   // B*T = 16*1000

// d_out float offsets
#define OUT_BH   0              // 16*1000*64   = 1,024,000
#define OUT_ZE   1024000        // 16*1000*256  = 4,096,000
#define OUT_ZQ   5120000        // 16*1000*256  = 4,096,000
#define OUT_IDX  9216000        // 16*1000*8    =   128,000
#define OUT_LOSS 9344000        // 1

// ws float offsets
#define WS_H     0              // 16000*512 = 8,192,000 floats
#define WS_CN    8192000        // 8*1024 = 8192 floats
#define WS_LOSS  8200192        // 1 float accumulator

// ---------------------------------------------------------------------------
// Tiled fp32 GEMM: C[M,N] = act(A[M,K] @ B[K,N] + bias[N])  (unchanged)
// ---------------------------------------------------------------------------
template<bool RELU>
__global__ __launch_bounds__(256) void gemm_bias_act(
    const float* __restrict__ A, const float* __restrict__ B,
    const float* __restrict__ bias, float* __restrict__ C,
    int M, int N, int K) {
  __shared__ float As[16][64];   // [k][m]
  __shared__ float Bs[16][64];   // [k][n]

  const int tx = threadIdx.x;          // 0..15
  const int ty = threadIdx.y;          // 0..15
  const int tid = ty * 16 + tx;
  const int row0 = blockIdx.y * 64;
  const int col0 = blockIdx.x * 64;

  const int arow = tid >> 2;           // 0..63
  const int akq  = (tid & 3) << 2;     // 0,4,8,12
  const int bkk  = tid >> 4;           // 0..15
  const int bcol = (tid & 15) << 2;    // 0..60

  float acc[4][4] = {};

  for (int k0 = 0; k0 < K; k0 += 16) {
    float4 av = *reinterpret_cast<const float4*>(
        &A[(size_t)(row0 + arow) * K + k0 + akq]);
    float4 bv = *reinterpret_cast<const float4*>(
        &B[(size_t)(k0 + bkk) * N + col0 + bcol]);
    __syncthreads();
    As[akq + 0][arow] = av.x;
    As[akq + 1][arow] = av.y;
    As[akq + 2][arow] = av.z;
    As[akq + 3][arow] = av.w;
    *reinterpret_cast<float4*>(&Bs[bkk][bcol]) = bv;
    __syncthreads();

#pragma unroll
    for (int kk = 0; kk < 16; ++kk) {
      float4 a = *reinterpret_cast<const float4*>(&As[kk][ty * 4]);
      float4 b = *reinterpret_cast<const float4*>(&Bs[kk][tx * 4]);
      float ar[4] = {a.x, a.y, a.z, a.w};
      float br[4] = {b.x, b.y, b.z, b.w};
#pragma unroll
      for (int i = 0; i < 4; ++i)
#pragma unroll
        for (int j = 0; j < 4; ++j)
          acc[i][j] = fmaf(ar[i], br[j], acc[i][j]);
    }
  }

  const float4 bb = *reinterpret_cast<const float4*>(&bias[col0 + tx * 4]);
  const float bias4[4] = {bb.x, bb.y, bb.z, bb.w};
#pragma unroll
  for (int i = 0; i < 4; ++i) {
    const int r = row0 + ty * 4 + i;
    float4 v;
    float* vp = &v.x;
#pragma unroll
    for (int j = 0; j < 4; ++j) {
      float t = acc[i][j] + bias4[j];
      if (RELU) t = fmaxf(t, 0.0f);
      vp[j] = t;
    }
    *reinterpret_cast<float4*>(&C[(size_t)r * N + col0 + tx * 4]) = v;
  }
}

// ---------------------------------------------------------------------------
// cn[g][k] = ||codebook[g][k]||^2 ; also zero the loss accumulator.
// ---------------------------------------------------------------------------
__global__ void cn_kernel(const float* __restrict__ cb, float* __restrict__ cn,
                          float* __restrict__ loss_acc) {
  const int i = blockIdx.x * 256 + threadIdx.x;
  if (i == 0) loss_acc[0] = 0.0f;
  if (i < GQ * KQ) {
    const float* c = cb + (size_t)i * GD;
    float s = 0.0f;
#pragma unroll
    for (int d = 0; d < GD; ++d) s = fmaf(c[d], c[d], s);
    cn[i] = s;
  }
}

// ---------------------------------------------------------------------------
// VQ, k-split version. Block = 256 threads = 4 waves; one group per block;
// 64 rows per block (lane = row). Wave w scans k in [w*256, (w+1)*256):
// k stays wave-uniform -> codebook reads remain scalar s_loads. Per-chunk
// (best,idx) merged through LDS in ascending-chunk order with strict '<'
// (preserves argmin first-min tie-break). The per-k dot product keeps the
// EXACT sequential fma order of the passing round-1 kernel, so distance
// values are bit-identical and no argmin decision can flip.
// Grid: (NROWS/64, GQ) = 250 x 8 = 2000 blocks = 8000 waves (~31/CU).
// ---------------------------------------------------------------------------
#define VQ_KCHUNK 256

__global__ __launch_bounds__(256) void vq_kernel(
    const float* __restrict__ z_e, const float* __restrict__ cb,
    const float* __restrict__ cn, float* __restrict__ z_q,
    float* __restrict__ idx_out, float* __restrict__ loss_acc) {
  const int g    = blockIdx.y;
  const int wave = threadIdx.x >> 6;   // 0..3  (k-chunk)
  const int lane = threadIdx.x & 63;   // row within tile
  const int n    = blockIdx.x * 64 + lane;   // NROWS % 64 == 0

  // Load this row's z sub-vector (32 floats) into registers.
  float z[GD];
  const float4* zv = reinterpret_cast<const float4*>(
      &z_e[(size_t)n * LATENT + g * GD]);
#pragma unroll
  for (int q = 0; q < 8; ++q) {
    float4 v = zv[q];
    z[q * 4 + 0] = v.x; z[q * 4 + 1] = v.y;
    z[q * 4 + 2] = v.z; z[q * 4 + 3] = v.w;
  }

  const float* cbg = cb + (size_t)g * KQ * GD;            // group codebook
  const float* cbw = cbg + (size_t)wave * VQ_KCHUNK * GD; // this wave's chunk
  const float* cnw = cn + (size_t)g * KQ + wave * VQ_KCHUNK;

  float best = 3.0e38f;
  int bidx = wave * VQ_KCHUNK;
#pragma unroll 2
  for (int k = 0; k < VQ_KCHUNK; ++k) {
    const float* c = cbw + k * GD;     // wave-uniform -> s_load
    float dot = 0.0f;
#pragma unroll
    for (int d = 0; d < GD; ++d) dot = fmaf(c[d], z[d], dot);
    const float dist = fmaf(-2.0f, dot, cnw[k]);
    if (dist < best) { best = dist; bidx = wave * VQ_KCHUNK + k; }
  }

  // Merge the 4 chunks through LDS (ascending chunk order = argmin tie-break)
  __shared__ float s_best[4][64];
  __shared__ int   s_idx[4][64];
  s_best[wave][lane] = best;
  s_idx[wave][lane]  = bidx;
  __syncthreads();

  float sse = 0.0f;
  if (wave == 0) {
    float mb = s_best[0][lane];
    int   mi = s_idx[0][lane];
#pragma unroll
    for (int c = 1; c < 4; ++c) {
      float v = s_best[c][lane];
      if (v < mb) { mb = v; mi = s_idx[c][lane]; }
    }

    // Gather chosen codeword, compute SSE, write z_q + idx.
    const float* c = cbg + (size_t)mi * GD;
    float cw[GD];
#pragma unroll
    for (int q = 0; q < 8; ++q) {
      float4 v = *reinterpret_cast<const float4*>(&c[q * 4]);
      cw[q * 4 + 0] = v.x; cw[q * 4 + 1] = v.y;
      cw[q * 4 + 2] = v.z; cw[q * 4 + 3] = v.w;
    }
#pragma unroll
    for (int d = 0; d < GD; ++d) {
      const float diff = cw[d] - z[d];
      sse = fmaf(diff, diff, sse);
    }
    float4* zq = reinterpret_cast<float4*>(&z_q[(size_t)n * LATENT + g * GD]);
#pragma unroll
    for (int q = 0; q < 8; ++q)
      zq[q] = make_float4(cw[q * 4], cw[q * 4 + 1], cw[q * 4 + 2], cw[q * 4 + 3]);
    idx_out[(size_t)n * GQ + g] = (float)mi;

    // Wave-level SSE reduction (64 lanes), one atomic per block.
#pragma unroll
    for (int off = 32; off > 0; off >>= 1)
      sse += __shfl_down(sse, off, 64);
    if (lane == 0) atomicAdd(loss_acc, sse);
  }
}

// vq_loss = 0.25*(codebook_loss + commit_loss) = 0.5 * total_sse / (NROWS*GD)
__global__ void loss_kernel(const float* __restrict__ acc,
                            float* __restrict__ out) {
  out[0] = 0.5f * acc[0] / (float)((size_t)NROWS * GD);
}

// ---------------------------------------------------------------------------
extern "C" void kernel_launch(void* const* d_in, const int* in_sizes, int n_in,
                              void* d_out, int out_size, void* d_ws, size_t ws_size,
                              hipStream_t stream) {
  const float* bands  = (const float*)d_in[0];
  const float* enc_w1 = (const float*)d_in[1];
  const float* enc_b1 = (const float*)d_in[2];
  const float* enc_w2 = (const float*)d_in[3];
  const float* enc_b2 = (const float*)d_in[4];
  const float* cbooks = (const float*)d_in[5];
  const float* dec_w1 = (const float*)d_in[6];
  const float* dec_b1 = (const float*)d_in[7];
  const float* dec_w2 = (const float*)d_in[8];
  const float* dec_b2 = (const float*)d_in[9];

  float* out = (float*)d_out;
  float* ws  = (float*)d_ws;

  float* bands_hat = out + OUT_BH;
  float* z_e       = out + OUT_ZE;
  float* z_q       = out + OUT_ZQ;
  float* idx_f     = out + OUT_IDX;
  float* loss_out  = out + OUT_LOSS;

  float* H        = ws + WS_H;
  float* cn       = ws + WS_CN;
  float* loss_acc = ws + WS_LOSS;

  const dim3 blk(16, 16);

  cn_kernel<<<dim3((GQ * KQ + 255) / 256), dim3(256), 0, stream>>>(cbooks, cn, loss_acc);

  gemm_bias_act<true ><<<dim3(HIDDEN / 64, NROWS / 64), blk, 0, stream>>>(
      bands, enc_w1, enc_b1, H, NROWS, HIDDEN, NBANDS);
  gemm_bias_act<false><<<dim3(LATENT / 64, NROWS / 64), blk, 0, stream>>>(
      H, enc_w2, enc_b2, z_e, NROWS, LATENT, HIDDEN);

  vq_kernel<<<dim3(NROWS / 64, GQ), dim3(256), 0, stream>>>(
      z_e, cbooks, cn, z_q, idx_f, loss_acc);

  gemm_bias_act<true ><<<dim3(HIDDEN / 64, NROWS / 64), blk, 0, stream>>>(
      z_q, dec_w1, dec_b1, H, NROWS, HIDDEN, LATENT);
  gemm_bias_act<false><<<dim3(NBANDS / 64, NROWS / 64), blk, 0, stream>>>(
      H, dec_w2, dec_b2, bands_hat, NROWS, NBANDS, HIDDEN);

  loss_kernel<<<1, 1, 0, stream>>>(loss_acc, loss_out);
}

// Round 3
// 375.366 us; speedup vs baseline: 2.1855x; 2.1855x over previous
//
#include <hip/hip_runtime.h>

// Problem constants
#define NBANDS 64
#define LATENT 256
#define HIDDEN 512
#define GQ 8
#define KQ 1024
#define GD 32
#define NROWS 16000   // B*T = 16*1000

// d_out float offsets
#define OUT_BH   0
#define OUT_ZE   1024000
#define OUT_ZQ   5120000
#define OUT_IDX  9216000
#define OUT_LOSS 9344000

// ws float offsets
#define WS_H     0
#define WS_CN    8192000
#define WS_LOSS  8200192

// ---------------------------------------------------------------------------
// Tiled fp32 GEMM: C[M,N] = act(A[M,K] @ B[K,N] + bias[N])  (unchanged)
// ---------------------------------------------------------------------------
template<bool RELU>
__global__ __launch_bounds__(256) void gemm_bias_act(
    const float* __restrict__ A, const float* __restrict__ B,
    const float* __restrict__ bias, float* __restrict__ C,
    int M, int N, int K) {
  __shared__ float As[16][64];
  __shared__ float Bs[16][64];

  const int tx = threadIdx.x;
  const int ty = threadIdx.y;
  const int tid = ty * 16 + tx;
  const int row0 = blockIdx.y * 64;
  const int col0 = blockIdx.x * 64;

  const int arow = tid >> 2;
  const int akq  = (tid & 3) << 2;
  const int bkk  = tid >> 4;
  const int bcol = (tid & 15) << 2;

  float acc[4][4] = {};

  for (int k0 = 0; k0 < K; k0 += 16) {
    float4 av = *reinterpret_cast<const float4*>(
        &A[(size_t)(row0 + arow) * K + k0 + akq]);
    float4 bv = *reinterpret_cast<const float4*>(
        &B[(size_t)(k0 + bkk) * N + col0 + bcol]);
    __syncthreads();
    As[akq + 0][arow] = av.x;
    As[akq + 1][arow] = av.y;
    As[akq + 2][arow] = av.z;
    As[akq + 3][arow] = av.w;
    *reinterpret_cast<float4*>(&Bs[bkk][bcol]) = bv;
    __syncthreads();

#pragma unroll
    for (int kk = 0; kk < 16; ++kk) {
      float4 a = *reinterpret_cast<const float4*>(&As[kk][ty * 4]);
      float4 b = *reinterpret_cast<const float4*>(&Bs[kk][tx * 4]);
      float ar[4] = {a.x, a.y, a.z, a.w};
      float br[4] = {b.x, b.y, b.z, b.w};
#pragma unroll
      for (int i = 0; i < 4; ++i)
#pragma unroll
        for (int j = 0; j < 4; ++j)
          acc[i][j] = fmaf(ar[i], br[j], acc[i][j]);
    }
  }

  const float4 bb = *reinterpret_cast<const float4*>(&bias[col0 + tx * 4]);
  const float bias4[4] = {bb.x, bb.y, bb.z, bb.w};
#pragma unroll
  for (int i = 0; i < 4; ++i) {
    const int r = row0 + ty * 4 + i;
    float4 v;
    float* vp = &v.x;
#pragma unroll
    for (int j = 0; j < 4; ++j) {
      float t = acc[i][j] + bias4[j];
      if (RELU) t = fmaxf(t, 0.0f);
      vp[j] = t;
    }
    *reinterpret_cast<float4*>(&C[(size_t)r * N + col0 + tx * 4]) = v;
  }
}

// ---------------------------------------------------------------------------
// cn[g][k] = ||codebook[g][k]||^2 ; also zero the loss accumulator.
// ---------------------------------------------------------------------------
__global__ void cn_kernel(const float* __restrict__ cb, float* __restrict__ cn,
                          float* __restrict__ loss_acc) {
  const int i = blockIdx.x * 256 + threadIdx.x;
  if (i == 0) loss_acc[0] = 0.0f;
  if (i < GQ * KQ) {
    const float* c = cb + (size_t)i * GD;
    float s = 0.0f;
#pragma unroll
    for (int d = 0; d < GD; ++d) s = fmaf(c[d], c[d], s);
    cn[i] = s;
  }
}

// ---------------------------------------------------------------------------
// VQ as register-tiled LDS GEMM + fused argmin.
// Block: 256 threads = (tx 0..15) x (ty 0..15). 128 rows/block, one group.
// Codebook staged in LDS in 8 chunks of 128 codewords; thread owns 8 rows
// (ty*8..+7) x 8 codewords (k%16==tx within chunk) -> 8x8 acc microtile.
// Per-(n,k) dot is the SAME sequential d=0..31 fma chain + fmaf(-2,dot,cn)
// as the passing round-1/2 kernels -> bit-identical distances -> identical
// argmin. Lexicographic (dist,idx) merge reproduces np.argmin first-min.
// No scalar-load dependence: all operands flow LDS -> VGPR.
// ---------------------------------------------------------------------------
#define VQ_ROWS 128
#define VQ_CHUNK 128
#define VQ_NCHUNK (KQ / VQ_CHUNK)   // 8
#define ZPAD 36                      // row stride (floats): 16B-aligned
#define MPAD 129                     // merge array stride

__global__ __launch_bounds__(256) void vq_kernel(
    const float* __restrict__ z_e, const float* __restrict__ cb,
    const float* __restrict__ cn, float* __restrict__ z_q,
    float* __restrict__ idx_out, float* __restrict__ loss_acc) {
  const int g    = blockIdx.y;
  const int row0 = blockIdx.x * VQ_ROWS;
  const int tid  = threadIdx.x;
  const int tx   = tid & 15;    // codeword subgroup (k % 16 == tx)
  const int ty   = tid >> 4;    // row octet (rows ty*8 .. ty*8+7)

  __shared__ float z_lds[VQ_ROWS][ZPAD];
  __shared__ float cb_lds[VQ_CHUNK][ZPAD];   // overlaid by merge arrays later
  __shared__ float cn_lds[VQ_CHUNK];

  const float* cbg = cb + (size_t)g * KQ * GD;
  const float* cng = cn + (size_t)g * KQ;

  // ---- stage z tile: thread t loads 16 floats of row (t>>1) ----
  {
    const int r   = tid >> 1;
    const int off = (tid & 1) << 4;
    const float4* src = reinterpret_cast<const float4*>(
        &z_e[(size_t)(row0 + r) * LATENT + g * GD + off]);
#pragma unroll
    for (int q = 0; q < 4; ++q)
      *reinterpret_cast<float4*>(&z_lds[r][off + q * 4]) = src[q];
  }

  float best[8];
  int   bidx[8];
#pragma unroll
  for (int i = 0; i < 8; ++i) { best[i] = 3.0e38f; bidx[i] = 0; }

  for (int ch = 0; ch < VQ_NCHUNK; ++ch) {
    __syncthreads();   // prev chunk reads done (covers z-stage on ch==0)
    // ---- stage codebook chunk + cn ----
    {
      const int kc  = tid >> 1;
      const int off = (tid & 1) << 4;
      const float4* src = reinterpret_cast<const float4*>(
          &cbg[(size_t)(ch * VQ_CHUNK + kc) * GD + off]);
#pragma unroll
      for (int q = 0; q < 4; ++q)
        *reinterpret_cast<float4*>(&cb_lds[kc][off + q * 4]) = src[q];
      if (tid < VQ_CHUNK) cn_lds[tid] = cng[ch * VQ_CHUNK + tid];
    }
    __syncthreads();

    // ---- 8x8 microtile GEMM over d ----
    float acc[8][8];
#pragma unroll
    for (int i = 0; i < 8; ++i)
#pragma unroll
      for (int j = 0; j < 8; ++j) acc[i][j] = 0.0f;

#pragma unroll 2
    for (int d0 = 0; d0 < GD; d0 += 4) {
      float4 a[8], b[8];
#pragma unroll
      for (int i = 0; i < 8; ++i)
        a[i] = *reinterpret_cast<const float4*>(&z_lds[ty * 8 + i][d0]);
#pragma unroll
      for (int j = 0; j < 8; ++j)
        b[j] = *reinterpret_cast<const float4*>(&cb_lds[j * 16 + tx][d0]);
#pragma unroll
      for (int i = 0; i < 8; ++i)
#pragma unroll
        for (int j = 0; j < 8; ++j) {
          float t = acc[i][j];
          t = fmaf(a[i].x, b[j].x, t);
          t = fmaf(a[i].y, b[j].y, t);
          t = fmaf(a[i].z, b[j].z, t);
          t = fmaf(a[i].w, b[j].w, t);
          acc[i][j] = t;
        }
    }

    // ---- distances + running argmin (ascending k within thread) ----
#pragma unroll
    for (int j = 0; j < 8; ++j) {
      const float cnv = cn_lds[j * 16 + tx];
      const int k = ch * VQ_CHUNK + j * 16 + tx;
#pragma unroll
      for (int i = 0; i < 8; ++i) {
        const float dist = fmaf(-2.0f, acc[i][j], cnv);
        if (dist < best[i]) { best[i] = dist; bidx[i] = k; }
      }
    }
  }

  // ---- merge 16 tx-partials per row (overlay onto cb_lds space) ----
  __syncthreads();   // all chunk compute done before overlay writes
  float* m_d = &cb_lds[0][0];                        // [16][MPAD]
  int*   m_i = reinterpret_cast<int*>(&cb_lds[0][0]) + 16 * MPAD + 16;
#pragma unroll
  for (int i = 0; i < 8; ++i) {
    m_d[tx * MPAD + ty * 8 + i] = best[i];
    m_i[tx * MPAD + ty * 8 + i] = bidx[i];
  }
  __syncthreads();

  float sse_part = 0.0f;
  if (tid < VQ_ROWS) {
    const int row = tid;
    float mb = m_d[row];
    int   mi = m_i[row];
#pragma unroll
    for (int t = 1; t < 16; ++t) {
      const float v = m_d[t * MPAD + row];
      const int  ix = m_i[t * MPAD + row];
      if (v < mb || (v == mb && ix < mi)) { mb = v; mi = ix; }
    }

    // gather codeword, SSE (same sequential order), write outputs
    const float* c = cbg + (size_t)mi * GD;
    float cw[GD];
#pragma unroll
    for (int q = 0; q < 8; ++q) {
      float4 v = *reinterpret_cast<const float4*>(&c[q * 4]);
      cw[q * 4 + 0] = v.x; cw[q * 4 + 1] = v.y;
      cw[q * 4 + 2] = v.z; cw[q * 4 + 3] = v.w;
    }
    float sse = 0.0f;
#pragma unroll
    for (int d = 0; d < GD; ++d) {
      const float diff = cw[d] - z_lds[row][d];
      sse = fmaf(diff, diff, sse);
    }
    float4* zq = reinterpret_cast<float4*>(
        &z_q[(size_t)(row0 + row) * LATENT + g * GD]);
#pragma unroll
    for (int q = 0; q < 8; ++q)
      zq[q] = make_float4(cw[q * 4], cw[q * 4 + 1], cw[q * 4 + 2], cw[q * 4 + 3]);
    idx_out[(size_t)(row0 + row) * GQ + g] = (float)mi;
    sse_part = sse;
  }

  // ---- block SSE reduction (reuse cn_lds), one atomic ----
  __syncthreads();
  if (tid < VQ_ROWS) cn_lds[tid] = sse_part;
  __syncthreads();
  if (tid < 64) {
    float s = cn_lds[tid] + cn_lds[tid + 64];
#pragma unroll
    for (int off = 32; off > 0; off >>= 1)
      s += __shfl_down(s, off, 64);
    if (tid == 0) atomicAdd(loss_acc, s);
  }
}

// vq_loss = 0.5 * total_sse / (NROWS*GD)
__global__ void loss_kernel(const float* __restrict__ acc,
                            float* __restrict__ out) {
  out[0] = 0.5f * acc[0] / (float)((size_t)NROWS * GD);
}

// ---------------------------------------------------------------------------
extern "C" void kernel_launch(void* const* d_in, const int* in_sizes, int n_in,
                              void* d_out, int out_size, void* d_ws, size_t ws_size,
                              hipStream_t stream) {
  const float* bands  = (const float*)d_in[0];
  const float* enc_w1 = (const float*)d_in[1];
  const float* enc_b1 = (const float*)d_in[2];
  const float* enc_w2 = (const float*)d_in[3];
  const float* enc_b2 = (const float*)d_in[4];
  const float* cbooks = (const float*)d_in[5];
  const float* dec_w1 = (const float*)d_in[6];
  const float* dec_b1 = (const float*)d_in[7];
  const float* dec_w2 = (const float*)d_in[8];
  const float* dec_b2 = (const float*)d_in[9];

  float* out = (float*)d_out;
  float* ws  = (float*)d_ws;

  float* bands_hat = out + OUT_BH;
  float* z_e       = out + OUT_ZE;
  float* z_q       = out + OUT_ZQ;
  float* idx_f     = out + OUT_IDX;
  float* loss_out  = out + OUT_LOSS;

  float* H        = ws + WS_H;
  float* cn       = ws + WS_CN;
  float* loss_acc = ws + WS_LOSS;

  const dim3 blk(16, 16);

  cn_kernel<<<dim3((GQ * KQ + 255) / 256), dim3(256), 0, stream>>>(cbooks, cn, loss_acc);

  gemm_bias_act<true ><<<dim3(HIDDEN / 64, NROWS / 64), blk, 0, stream>>>(
      bands, enc_w1, enc_b1, H, NROWS, HIDDEN, NBANDS);
  gemm_bias_act<false><<<dim3(LATENT / 64, NROWS / 64), blk, 0, stream>>>(
      H, enc_w2, enc_b2, z_e, NROWS, LATENT, HIDDEN);

  vq_kernel<<<dim3(NROWS / VQ_ROWS, GQ), dim3(256), 0, stream>>>(
      z_e, cbooks, cn, z_q, idx_f, loss_acc);

  gemm_bias_act<true ><<<dim3(HIDDEN / 64, NROWS / 64), blk, 0, stream>>>(
      z_q, dec_w1, dec_b1, H, NROWS, HIDDEN, LATENT);
  gemm_bias_act<false><<<dim3(NBANDS / 64, NROWS / 64), blk, 0, stream>>>(
      H, dec_w2, dec_b2, bands_hat, NROWS, NBANDS, HIDDEN);

  loss_kernel<<<1, 1, 0, stream>>>(loss_acc, loss_out);
}

// Round 5
// 322.536 us; speedup vs baseline: 2.5435x; 1.1638x over previous
//
#include <hip/hip_runtime.h>

// Problem constants
#define NBANDS 64
#define LATENT 256
#define HIDDEN 512
#define GQ 8
#define KQ 1024
#define GD 32
#define NROWS 16000   // B*T = 16*1000

// d_out float offsets
#define OUT_BH   0
#define OUT_ZE   1024000
#define OUT_ZQ   5120000
#define OUT_IDX  9216000
#define OUT_LOSS 9344000

// ws float offsets.  The fp32 H region [0, 8192000) is dead after enc2;
// decoder-side bf16 buffers are overlaid inside it (total ws usage unchanged
// vs the proven round-1..3 footprint):
//   H2BF  : ushort[8,192,000]  -> floats [0, 4096000)
//   ZQB   : ushort[4,096,000]  -> floats [4096000, 6144000)
//   W1B   : ushort[131072]     -> floats [6144000, 6209536)
//   W2B   : ushort[32768]      -> floats [6209536, 6225920)
#define WS_H     0
#define WS_H2BF_F  0
#define WS_ZQB_F   4096000
#define WS_W1B_F   6144000
#define WS_W2B_F   6209536
#define WS_CN    8192000
#define WS_LOSS  8200192

typedef __attribute__((ext_vector_type(8))) short bf16x8;
typedef __attribute__((ext_vector_type(4))) float f32x4;

__device__ __forceinline__ unsigned short f2bf(float f) {
  unsigned u = __builtin_bit_cast(unsigned, f);
  unsigned r = u + 0x7FFFu + ((u >> 16) & 1u);   // RNE; inputs finite
  return (unsigned short)(r >> 16);
}

// ---------------------------------------------------------------------------
// fp32 GEMM, 128xBN tile, TMxTN microtile, BK=16, 256 threads.
// C[M,N] = act(A[M,K] @ B[K,N] + bias[N]).  M%128==0, N%BN==0, K%16==0.
// enc1: BN=128,TM=8,TN=8 ; enc2: BN=64,TM=4,TN=8.
// ---------------------------------------------------------------------------
template<int BN, int TM, int TN, bool RELU>
__global__ __launch_bounds__(256) void gemm_f32(
    const float* __restrict__ A, const float* __restrict__ B,
    const float* __restrict__ bias, float* __restrict__ C,
    int M, int N, int K) {
  constexpr int BM = 128;
  constexpr int BK = 16;
  constexpr int NTX = BN / TN;

  __shared__ float As[BK][BM + 8];   // [k][m], pad 8 (2-way max on writes)
  __shared__ float Bs[BK][BN + 4];   // [k][n], pad 4 keeps float4 align

  const int tid = threadIdx.x;
  const int tx = tid % NTX;
  const int ty = tid / NTX;
  const int row0 = blockIdx.y * BM;
  const int col0 = blockIdx.x * BN;

  // A-staging map: 128 rows x 16 k = 2048 floats, 8 per thread
  const int arow = tid >> 1;
  const int akq  = (tid & 1) * 8;
  // B-staging map
  const int bkk = tid >> 4;              // 0..15
  const int bn  = (tid & 15) * (BN / 16);

  float acc[TM][TN] = {};

  for (int k0 = 0; k0 < K; k0 += BK) {
    float4 av0 = *reinterpret_cast<const float4*>(
        &A[(size_t)(row0 + arow) * K + k0 + akq]);
    float4 av1 = *reinterpret_cast<const float4*>(
        &A[(size_t)(row0 + arow) * K + k0 + akq + 4]);
    float4 bv0, bv1;
    bv0 = *reinterpret_cast<const float4*>(
        &B[(size_t)(k0 + bkk) * N + col0 + bn]);
    if (BN == 128)
      bv1 = *reinterpret_cast<const float4*>(
          &B[(size_t)(k0 + bkk) * N + col0 + bn + 4]);
    __syncthreads();   // previous iteration's LDS reads complete
    As[akq + 0][arow] = av0.x; As[akq + 1][arow] = av0.y;
    As[akq + 2][arow] = av0.z; As[akq + 3][arow] = av0.w;
    As[akq + 4][arow] = av1.x; As[akq + 5][arow] = av1.y;
    As[akq + 6][arow] = av1.z; As[akq + 7][arow] = av1.w;
    *reinterpret_cast<float4*>(&Bs[bkk][bn]) = bv0;
    if (BN == 128)
      *reinterpret_cast<float4*>(&Bs[bkk][bn + 4]) = bv1;
    __syncthreads();

#pragma unroll
    for (int kk = 0; kk < BK; ++kk) {
      float a[TM], b[TN];
#pragma unroll
      for (int q = 0; q < TM / 4; ++q) {
        float4 v = *reinterpret_cast<const float4*>(&As[kk][ty * TM + q * 4]);
        a[q * 4 + 0] = v.x; a[q * 4 + 1] = v.y;
        a[q * 4 + 2] = v.z; a[q * 4 + 3] = v.w;
      }
#pragma unroll
      for (int q = 0; q < TN / 4; ++q) {
        float4 v = *reinterpret_cast<const float4*>(&Bs[kk][tx * TN + q * 4]);
        b[q * 4 + 0] = v.x; b[q * 4 + 1] = v.y;
        b[q * 4 + 2] = v.z; b[q * 4 + 3] = v.w;
      }
#pragma unroll
      for (int i = 0; i < TM; ++i)
#pragma unroll
        for (int j = 0; j < TN; ++j)
          acc[i][j] = fmaf(a[i], b[j], acc[i][j]);
    }
  }

  // epilogue
  float bb[TN];
#pragma unroll
  for (int q = 0; q < TN / 4; ++q) {
    float4 v = *reinterpret_cast<const float4*>(&bias[col0 + tx * TN + q * 4]);
    bb[q * 4 + 0] = v.x; bb[q * 4 + 1] = v.y;
    bb[q * 4 + 2] = v.z; bb[q * 4 + 3] = v.w;
  }
#pragma unroll
  for (int i = 0; i < TM; ++i) {
    const int r = row0 + ty * TM + i;
#pragma unroll
    for (int q = 0; q < TN / 4; ++q) {
      float4 v;
      float* vp = &v.x;
#pragma unroll
      for (int j = 0; j < 4; ++j) {
        float t = acc[i][q * 4 + j] + bb[q * 4 + j];
        if (RELU) t = fmaxf(t, 0.0f);
        vp[j] = t;
      }
      *reinterpret_cast<float4*>(&C[(size_t)r * N + col0 + tx * TN + q * 4]) = v;
    }
  }
}

// ---------------------------------------------------------------------------
// bf16 MFMA GEMM: tile BM=4*WM rows x 64 cols, BK=32, 256 threads (4 waves,
// wave w owns rows [w*WM, (w+1)*WM)).  A[M,K], B[K,N] bf16 row-major; fp32
// accumulate.  OUT_BF16: +bias, relu, bf16 store; else +bias, f32 store.
// Fragment layouts (mfma_f32_16x16x32_bf16, m89/m91-verified C/D):
//   A: lane holds A[m=lane&15][k=quad*8+j]   B: lane holds B[k=quad*8+j][n=lane&15]
//   D: col=lane&15, row=quad*4+reg
// ---------------------------------------------------------------------------
template<int WM, bool OUT_BF16>
__global__ __launch_bounds__(256) void gemm_bf16_mfma(
    const unsigned short* __restrict__ A, const unsigned short* __restrict__ B,
    const float* __restrict__ bias, void* __restrict__ Cout,
    int M, int N, int K) {
  constexpr int BM = 4 * WM;
  constexpr int MT = WM / 16;

  __shared__ unsigned short As[BM][40];   // [m][k], pad to 40 (breaks 8-way)
  __shared__ unsigned short Bs[64][40];   // [n][k] (transposed), pad 40

  const int tid  = threadIdx.x;
  const int wave = tid >> 6;
  const int lane = tid & 63;
  const int quad = lane >> 4;
  const int l16  = lane & 15;
  const int row0 = blockIdx.y * BM;
  const int col0 = blockIdx.x * 64;

  f32x4 acc[MT][4];
#pragma unroll
  for (int mt = 0; mt < MT; ++mt)
#pragma unroll
    for (int nt = 0; nt < 4; ++nt) acc[mt][nt] = (f32x4){0.f, 0.f, 0.f, 0.f};

  for (int k0 = 0; k0 < K; k0 += 32) {
    __syncthreads();
    // stage A tile (BM x 32 bf16)
    if constexpr (BM == 128) {
      const int r = tid >> 1, seg = (tid & 1) * 16;
      const uint4* src = reinterpret_cast<const uint4*>(
          &A[(size_t)(row0 + r) * K + k0 + seg]);
      uint4* dst = reinterpret_cast<uint4*>(&As[r][seg]);
      dst[0] = src[0]; dst[1] = src[1];
    } else {
      const int r = tid >> 2, seg = (tid & 3) * 8;
      *reinterpret_cast<uint4*>(&As[r][seg]) =
          *reinterpret_cast<const uint4*>(&A[(size_t)(row0 + r) * K + k0 + seg]);
    }
    // stage B tile (32 k x 64 n), transposed into Bs[n][k]
    {
      const int kk = tid >> 3, n0 = (tid & 7) * 8;
      uint4 bv = *reinterpret_cast<const uint4*>(
          &B[(size_t)(k0 + kk) * N + col0 + n0]);
      unsigned short t[8];
      *reinterpret_cast<uint4*>(t) = bv;
#pragma unroll
      for (int j = 0; j < 8; ++j) Bs[n0 + j][kk] = t[j];
    }
    __syncthreads();

    bf16x8 af[MT], bf[4];
#pragma unroll
    for (int mt = 0; mt < MT; ++mt)
      af[mt] = *reinterpret_cast<const bf16x8*>(
          &As[wave * WM + mt * 16 + l16][quad * 8]);
#pragma unroll
    for (int nt = 0; nt < 4; ++nt)
      bf[nt] = *reinterpret_cast<const bf16x8*>(&Bs[nt * 16 + l16][quad * 8]);
#pragma unroll
    for (int mt = 0; mt < MT; ++mt)
#pragma unroll
      for (int nt = 0; nt < 4; ++nt)
        acc[mt][nt] = __builtin_amdgcn_mfma_f32_16x16x32_bf16(
            af[mt], bf[nt], acc[mt][nt], 0, 0, 0);
  }

  // epilogue
#pragma unroll
  for (int mt = 0; mt < MT; ++mt)
#pragma unroll
    for (int nt = 0; nt < 4; ++nt) {
      const int col = col0 + nt * 16 + l16;
      const float bv = bias[col];
#pragma unroll
      for (int r = 0; r < 4; ++r) {
        const int grow = row0 + wave * WM + mt * 16 + quad * 4 + r;
        float v = acc[mt][nt][r] + bv;
        if constexpr (OUT_BF16) {
          v = fmaxf(v, 0.0f);
          ((unsigned short*)Cout)[(size_t)grow * N + col] = f2bf(v);
        } else {
          ((float*)Cout)[(size_t)grow * N + col] = v;
        }
      }
    }
}

// ---------------------------------------------------------------------------
// cn[g][k] = ||codebook[g][k]||^2 ; also zero the loss accumulator.
// ---------------------------------------------------------------------------
__global__ void cn_kernel(const float* __restrict__ cb, float* __restrict__ cn,
                          float* __restrict__ loss_acc) {
  const int i = blockIdx.x * 256 + threadIdx.x;
  if (i == 0) loss_acc[0] = 0.0f;
  if (i < GQ * KQ) {
    const float* c = cb + (size_t)i * GD;
    float s = 0.0f;
#pragma unroll
    for (int d = 0; d < GD; ++d) s = fmaf(c[d], c[d], s);
    cn[i] = s;
  }
}

// Convert decoder weights to bf16 (w1: 131072, w2: 32768) in one launch.
__global__ void wconv_kernel(const float* __restrict__ w1, const float* __restrict__ w2,
                             unsigned short* __restrict__ w1b,
                             unsigned short* __restrict__ w2b) {
  const int i = blockIdx.x * 256 + threadIdx.x;
  const int n1 = LATENT * HIDDEN;        // 131072
  const int n2 = HIDDEN * NBANDS;        // 32768
  if (i < n1) w1b[i] = f2bf(w1[i]);
  else if (i < n1 + n2) w2b[i - n1] = f2bf(w2[i - n1]);
}

// ---------------------------------------------------------------------------
// VQ as register-tiled LDS GEMM + fused argmin (unchanged from round 3,
// plus a bf16 copy of z_q emitted for the MFMA decoder).
// ---------------------------------------------------------------------------
#define VQ_ROWS 128
#define VQ_CHUNK 128
#define VQ_NCHUNK (KQ / VQ_CHUNK)
#define ZPAD 36
#define MPAD 129

__global__ __launch_bounds__(256) void vq_kernel(
    const float* __restrict__ z_e, const float* __restrict__ cb,
    const float* __restrict__ cn, float* __restrict__ z_q,
    unsigned short* __restrict__ zqb,
    float* __restrict__ idx_out, float* __restrict__ loss_acc) {
  const int g    = blockIdx.y;
  const int row0 = blockIdx.x * VQ_ROWS;
  const int tid  = threadIdx.x;
  const int tx   = tid & 15;
  const int ty   = tid >> 4;

  __shared__ float z_lds[VQ_ROWS][ZPAD];
  __shared__ float cb_lds[VQ_CHUNK][ZPAD];
  __shared__ float cn_lds[VQ_CHUNK];

  const float* cbg = cb + (size_t)g * KQ * GD;
  const float* cng = cn + (size_t)g * KQ;

  {
    const int r   = tid >> 1;
    const int off = (tid & 1) << 4;
    const float4* src = reinterpret_cast<const float4*>(
        &z_e[(size_t)(row0 + r) * LATENT + g * GD + off]);
#pragma unroll
    for (int q = 0; q < 4; ++q)
      *reinterpret_cast<float4*>(&z_lds[r][off + q * 4]) = src[q];
  }

  float best[8];
  int   bidx[8];
#pragma unroll
  for (int i = 0; i < 8; ++i) { best[i] = 3.0e38f; bidx[i] = 0; }

  for (int ch = 0; ch < VQ_NCHUNK; ++ch) {
    __syncthreads();
    {
      const int kc  = tid >> 1;
      const int off = (tid & 1) << 4;
      const float4* src = reinterpret_cast<const float4*>(
          &cbg[(size_t)(ch * VQ_CHUNK + kc) * GD + off]);
#pragma unroll
      for (int q = 0; q < 4; ++q)
        *reinterpret_cast<float4*>(&cb_lds[kc][off + q * 4]) = src[q];
      if (tid < VQ_CHUNK) cn_lds[tid] = cng[ch * VQ_CHUNK + tid];
    }
    __syncthreads();

    float acc[8][8];
#pragma unroll
    for (int i = 0; i < 8; ++i)
#pragma unroll
      for (int j = 0; j < 8; ++j) acc[i][j] = 0.0f;

#pragma unroll 2
    for (int d0 = 0; d0 < GD; d0 += 4) {
      float4 a[8], b[8];
#pragma unroll
      for (int i = 0; i < 8; ++i)
        a[i] = *reinterpret_cast<const float4*>(&z_lds[ty * 8 + i][d0]);
#pragma unroll
      for (int j = 0; j < 8; ++j)
        b[j] = *reinterpret_cast<const float4*>(&cb_lds[j * 16 + tx][d0]);
#pragma unroll
      for (int i = 0; i < 8; ++i)
#pragma unroll
        for (int j = 0; j < 8; ++j) {
          float t = acc[i][j];
          t = fmaf(a[i].x, b[j].x, t);
          t = fmaf(a[i].y, b[j].y, t);
          t = fmaf(a[i].z, b[j].z, t);
          t = fmaf(a[i].w, b[j].w, t);
          acc[i][j] = t;
        }
    }

#pragma unroll
    for (int j = 0; j < 8; ++j) {
      const float cnv = cn_lds[j * 16 + tx];
      const int k = ch * VQ_CHUNK + j * 16 + tx;
#pragma unroll
      for (int i = 0; i < 8; ++i) {
        const float dist = fmaf(-2.0f, acc[i][j], cnv);
        if (dist < best[i]) { best[i] = dist; bidx[i] = k; }
      }
    }
  }

  __syncthreads();
  float* m_d = &cb_lds[0][0];
  int*   m_i = reinterpret_cast<int*>(&cb_lds[0][0]) + 16 * MPAD + 16;
#pragma unroll
  for (int i = 0; i < 8; ++i) {
    m_d[tx * MPAD + ty * 8 + i] = best[i];
    m_i[tx * MPAD + ty * 8 + i] = bidx[i];
  }
  __syncthreads();

  float sse_part = 0.0f;
  if (tid < VQ_ROWS) {
    const int row = tid;
    float mb = m_d[row];
    int   mi = m_i[row];
#pragma unroll
    for (int t = 1; t < 16; ++t) {
      const float v = m_d[t * MPAD + row];
      const int  ix = m_i[t * MPAD + row];
      if (v < mb || (v == mb && ix < mi)) { mb = v; mi = ix; }
    }

    const float* c = cbg + (size_t)mi * GD;
    float cw[GD];
#pragma unroll
    for (int q = 0; q < 8; ++q) {
      float4 v = *reinterpret_cast<const float4*>(&c[q * 4]);
      cw[q * 4 + 0] = v.x; cw[q * 4 + 1] = v.y;
      cw[q * 4 + 2] = v.z; cw[q * 4 + 3] = v.w;
    }
    float sse = 0.0f;
#pragma unroll
    for (int d = 0; d < GD; ++d) {
      const float diff = cw[d] - z_lds[row][d];
      sse = fmaf(diff, diff, sse);
    }
    float4* zq = reinterpret_cast<float4*>(
        &z_q[(size_t)(row0 + row) * LATENT + g * GD]);
#pragma unroll
    for (int q = 0; q < 8; ++q)
      zq[q] = make_float4(cw[q * 4], cw[q * 4 + 1], cw[q * 4 + 2], cw[q * 4 + 3]);

    // bf16 copy for the MFMA decoder
    alignas(16) unsigned short zb[GD];
#pragma unroll
    for (int d = 0; d < GD; ++d) zb[d] = f2bf(cw[d]);
    uint4* dstb = reinterpret_cast<uint4*>(
        zqb + (size_t)(row0 + row) * LATENT + g * GD);
    const uint4* srcb = reinterpret_cast<const uint4*>(zb);
#pragma unroll
    for (int q = 0; q < 4; ++q) dstb[q] = srcb[q];

    idx_out[(size_t)(row0 + row) * GQ + g] = (float)mi;
    sse_part = sse;
  }

  __syncthreads();
  if (tid < VQ_ROWS) cn_lds[tid] = sse_part;
  __syncthreads();
  if (tid < 64) {
    float s = cn_lds[tid] + cn_lds[tid + 64];
#pragma unroll
    for (int off = 32; off > 0; off >>= 1)
      s += __shfl_down(s, off, 64);
    if (tid == 0) atomicAdd(loss_acc, s);
  }
}

__global__ void loss_kernel(const float* __restrict__ acc,
                            float* __restrict__ out) {
  out[0] = 0.5f * acc[0] / (float)((size_t)NROWS * GD);
}

// ---------------------------------------------------------------------------
extern "C" void kernel_launch(void* const* d_in, const int* in_sizes, int n_in,
                              void* d_out, int out_size, void* d_ws, size_t ws_size,
                              hipStream_t stream) {
  const float* bands  = (const float*)d_in[0];
  const float* enc_w1 = (const float*)d_in[1];
  const float* enc_b1 = (const float*)d_in[2];
  const float* enc_w2 = (const float*)d_in[3];
  const float* enc_b2 = (const float*)d_in[4];
  const float* cbooks = (const float*)d_in[5];
  const float* dec_w1 = (const float*)d_in[6];
  const float* dec_b1 = (const float*)d_in[7];
  const float* dec_w2 = (const float*)d_in[8];
  const float* dec_b2 = (const float*)d_in[9];

  float* out = (float*)d_out;
  float* ws  = (float*)d_ws;

  float* bands_hat = out + OUT_BH;
  float* z_e       = out + OUT_ZE;
  float* z_q       = out + OUT_ZQ;
  float* idx_f     = out + OUT_IDX;
  float* loss_out  = out + OUT_LOSS;

  float* H        = ws + WS_H;
  float* cn       = ws + WS_CN;
  float* loss_acc = ws + WS_LOSS;
  unsigned short* h2bf = (unsigned short*)(ws + WS_H2BF_F);
  unsigned short* zqb  = (unsigned short*)(ws + WS_ZQB_F);
  unsigned short* w1b  = (unsigned short*)(ws + WS_W1B_F);
  unsigned short* w2b  = (unsigned short*)(ws + WS_W2B_F);

  cn_kernel<<<dim3((GQ * KQ + 255) / 256), dim3(256), 0, stream>>>(cbooks, cn, loss_acc);

  // Encoder (fp32, retiled): H = relu(bands@W1+b1); z_e = H@W2+b2
  gemm_f32<128, 8, 8, true ><<<dim3(HIDDEN / 128, NROWS / 128), dim3(256), 0, stream>>>(
      bands, enc_w1, enc_b1, H, NROWS, HIDDEN, NBANDS);
  gemm_f32<64, 4, 8, false><<<dim3(LATENT / 64, NROWS / 128), dim3(256), 0, stream>>>(
      H, enc_w2, enc_b2, z_e, NROWS, LATENT, HIDDEN);

  // Decoder weights -> bf16 (H fp32 is dead now; bf16 buffers overlay it)
  wconv_kernel<<<dim3((LATENT * HIDDEN + HIDDEN * NBANDS + 255) / 256), dim3(256), 0, stream>>>(
      dec_w1, dec_w2, w1b, w2b);

  // VQ (fp32 exact; also emits bf16 z_q)
  vq_kernel<<<dim3(NROWS / VQ_ROWS, GQ), dim3(256), 0, stream>>>(
      z_e, cbooks, cn, z_q, zqb, idx_f, loss_acc);

  // Decoder (bf16 MFMA): H2 = relu(z_q@W1+b1) [bf16]; bands_hat = H2@W2+b2 [f32]
  gemm_bf16_mfma<32, true ><<<dim3(HIDDEN / 64, NROWS / 128), dim3(256), 0, stream>>>(
      zqb, w1b, dec_b1, (void*)h2bf, NROWS, HIDDEN, LATENT);
  gemm_bf16_mfma<16, false><<<dim3(NBANDS / 64, NROWS / 64), dim3(256), 0, stream>>>(
      h2bf, w2b, dec_b2, (void*)bands_hat, NROWS, NBANDS, HIDDEN);

  loss_kernel<<<1, 1, 0, stream>>>(loss_acc, loss_out);
}